// Round 1
// baseline (153.346 us; speedup 1.0000x reference)
//
#include <hip/hip_runtime.h>

// Correlation loss: 800 patches of 16x16 from msi (first 32 of 64 ch) and he (3 ch).
// Key identity: dm - dh = s[p] + s[q] - 2*(gm - gh), s = sum(pm^2) - sum(ph^2),
// g = signed gram over 35 channels (+ for 32 msi ch, - for 3 he ch).
// One block per patch, 256 threads, 4x4 register tile of the 256x256 pair matrix.

#define WS   16
#define PSZ  256          // WS*WS columns per patch
#define CM   32           // msi channels used (u//2)
#define CHE  3            // he channels
#define CT   35           // total signed-gram channels
#define IMG  512
#define IMG2 (IMG * IMG)

__global__ __launch_bounds__(256, 2)
void corr_loss_kernel(const float* __restrict__ msi,
                      const float* __restrict__ he,
                      const int* __restrict__ i_idx,
                      const int* __restrict__ j_idx,
                      float* __restrict__ out,
                      float scale)
{
    // [c][q] layout: own-column reads are lane-contiguous (conflict-free),
    // p-column reads are all-lane broadcast (free).
    __shared__ __align__(16) float xs[CT * PSZ];
    __shared__ __align__(16) float s_lds[PSZ];   // sum(pm^2) - sum(ph^2) per column
    __shared__ __align__(16) float m_lds[PSZ];   // mask per column
    __shared__ float red[4];

    const int b = blockIdx.x;
    const int t = threadIdx.x;
    const int i0 = i_idx[b];
    const int j0 = j_idx[b];

    // ---- stage patch column q = t into LDS, compute s and mask inline ----
    {
        const int r  = t >> 4;        // row within window
        const int cc = t & 15;        // col within window
        const float* mp = msi + (size_t)(i0 + r) * IMG + (j0 + cc);
        float sqm = 0.f;
#pragma unroll
        for (int c = 0; c < CM; ++c) {
            float v = mp[(size_t)c * IMG2];
            xs[c * PSZ + t] = v;
            sqm = fmaf(v, v, sqm);
        }
        const float* hp = he + (size_t)(i0 + r) * IMG + (j0 + cc);
        float sqh = 0.f, hsum = 0.f;
#pragma unroll
        for (int c = 0; c < CHE; ++c) {
            float v = hp[(size_t)c * IMG2];
            xs[(CM + c) * PSZ + t] = v;
            sqh = fmaf(v, v, sqh);
            hsum += v;
        }
        s_lds[t] = sqm - sqh;
        m_lds[t] = (hsum >= 0.05f) ? 1.0f : 0.0f;
    }
    __syncthreads();

    const int lane = t & 63;
    const int w    = t >> 6;
    const int q0   = lane << 2;       // this thread's 4 q-columns (same across waves)

    // own-column fragments in registers: a[35][4]  (~140 VGPRs, fully unrolled use)
    float a[CT][4];
#pragma unroll
    for (int c = 0; c < CT; ++c) {
        float4 v = *(const float4*)&xs[c * PSZ + q0];
        a[c][0] = v.x; a[c][1] = v.y; a[c][2] = v.z; a[c][3] = v.w;
    }
    float4 sqv = *(const float4*)&s_lds[q0];
    float4 mqv = *(const float4*)&m_lds[q0];
    const float sq[4] = {sqv.x, sqv.y, sqv.z, sqv.w};
    const float mq[4] = {mqv.x, mqv.y, mqv.z, mqv.w};

    float acc = 0.f;
    // wave w handles p-tiles {w, w+4, ..., w+60}: b-loads are whole-wave broadcast
    for (int k = 0; k < 16; ++k) {
        const int p0 = (w << 2) + (k << 4);
        float g[4][4] = {{0.f}};
#pragma unroll
        for (int c = 0; c < CT; ++c) {
            float4 b4 = *(const float4*)&xs[c * PSZ + p0];
            float bv[4] = {b4.x, b4.y, b4.z, b4.w};
#pragma unroll
            for (int ii = 0; ii < 4; ++ii)
#pragma unroll
                for (int jj = 0; jj < 4; ++jj)
                    g[ii][jj] = (c < CM)
                        ? fmaf( a[c][ii], bv[jj], g[ii][jj])    // msi: +gram
                        : fmaf(-a[c][ii], bv[jj], g[ii][jj]);   // he: -gram
        }
        float4 spv = *(const float4*)&s_lds[p0];
        float4 mpv = *(const float4*)&m_lds[p0];
        const float sp[4] = {spv.x, spv.y, spv.z, spv.w};
        const float mp[4] = {mpv.x, mpv.y, mpv.z, mpv.w};
#pragma unroll
        for (int ii = 0; ii < 4; ++ii)
#pragma unroll
            for (int jj = 0; jj < 4; ++jj) {
                float d = sq[ii] + sp[jj] - 2.0f * g[ii][jj];
                acc = fmaf(mq[ii] * mp[jj], fabsf(d), acc);
            }
    }

    // block reduction: wave shuffle -> LDS -> one atomic per block
#pragma unroll
    for (int off = 32; off > 0; off >>= 1)
        acc += __shfl_down(acc, off, 64);
    if (lane == 0) red[w] = acc;
    __syncthreads();
    if (t == 0)
        atomicAdd(out, (red[0] + red[1] + red[2] + red[3]) * scale);
}

extern "C" void kernel_launch(void* const* d_in, const int* in_sizes, int n_in,
                              void* d_out, int out_size, void* d_ws, size_t ws_size,
                              hipStream_t stream) {
    const float* msi   = (const float*)d_in[0];
    const float* he    = (const float*)d_in[1];
    const int*   i_idx = (const int*)d_in[2];
    const int*   j_idx = (const int*)d_in[3];
    const int    NB    = in_sizes[2];   // 800 patches
    float*       out   = (float*)d_out;

    // d_out is re-poisoned (0xAA) before every timed launch -> zero it here.
    hipMemsetAsync(out, 0, sizeof(float) * out_size, stream);

    // mean over 256*256 pairs per patch, then sum / (batch // 5)
    const float scale = 1.0f / ((float)(PSZ * PSZ) * (float)(NB / 5));
    corr_loss_kernel<<<NB, 256, 0, stream>>>(msi, he, i_idx, j_idx, out, scale);
}

// Round 2
// 113.219 us; speedup vs baseline: 1.3544x; 1.3544x over previous
//
#include <hip/hip_runtime.h>
#include <hip/hip_bf16.h>

// Correlation loss via bf16 MFMA.
// dm - dh = s[p] + s[q] - 2*(g_m - g_h),  s = sum(pm^2) - sum(ph^2).
// g_m: 256x256x32 gram of msi (bf16 MFMA 16x16x32, K=32 exactly).
// g_h: he gram, folded into the SAME accumulator by a first MFMA with
//      A = -he (k0..2 of 32, rest zero), B = +he  ->  acc starts at -g_h.
// Output sum is symmetric in (p,q): G symmetric, s_p+s_q symmetric, masks
// symmetric -> any C-layout row/col transpose cancels exactly.
// One block per patch: 4 waves x (4 row-tiles x 16 col-tiles) of 16x16.

#define WS   16
#define PSZ  256
#define IMG  512
#define IMG2 (IMG * IMG)
#define XSTR 40          // ushorts per xs row = 80 B: 16B-aligned, bank-rotating

typedef __attribute__((ext_vector_type(8))) short short8;
typedef __attribute__((ext_vector_type(4))) float float4v;

static __device__ __forceinline__ unsigned short f2bf(float v) {
    union { __hip_bfloat16 b; unsigned short u; } cv;
    cv.b = __float2bfloat16(v);
    return cv.u;
}
static __device__ __forceinline__ float bf2f(unsigned short u) {
    union { unsigned int u; float f; } cv;
    cv.u = ((unsigned int)u) << 16;
    return cv.f;
}

__global__ __launch_bounds__(256, 2)
void corr_loss_kernel(const float* __restrict__ msi,
                      const float* __restrict__ he,
                      const int* __restrict__ i_idx,
                      const int* __restrict__ j_idx,
                      float* __restrict__ out,
                      float scale)
{
    __shared__ __align__(16) unsigned short xs[PSZ * XSTR];   // 20480 B msi bf16 [p][k]
    __shared__ __align__(16) unsigned short heA[PSZ * 8];     // 4096 B  -he  [p][k0..7]
    __shared__ __align__(16) unsigned short heB[PSZ * 8];     // 4096 B  +he
    __shared__ __align__(16) unsigned int   zq[4];            // 16 B zeros (k8..31 frag)
    __shared__ __align__(16) float s_lds[PSZ];
    __shared__ __align__(16) float m_lds[PSZ];
    __shared__ float red[4];

    const int b = blockIdx.x;
    const int t = threadIdx.x;
    const int i0 = i_idx[b], j0 = j_idx[b];

    // ---- stage column p = t: bf16-round msi, +/-he, s and mask ----
    {
        const int r = t >> 4, c = t & 15;
        const float* mp = msi + (size_t)(i0 + r) * IMG + (j0 + c);
        float sm = 0.f;
#pragma unroll
        for (int g = 0; g < 4; ++g) {
            float v[8];
#pragma unroll
            for (int k = 0; k < 8; ++k) v[k] = mp[(size_t)(g * 8 + k) * IMG2];
            unsigned int pk[4];
#pragma unroll
            for (int k = 0; k < 4; ++k) {
                unsigned short lo = f2bf(v[2 * k]), hi = f2bf(v[2 * k + 1]);
                float fl = bf2f(lo), fh = bf2f(hi);
                sm = fmaf(fl, fl, sm);
                sm = fmaf(fh, fh, sm);
                pk[k] = (unsigned int)lo | ((unsigned int)hi << 16);
            }
            *(uint4*)&xs[t * XSTR + g * 8] = make_uint4(pk[0], pk[1], pk[2], pk[3]);
        }
        const float* hp = he + (size_t)(i0 + r) * IMG + (j0 + c);
        float hsum = 0.f, sh = 0.f;
        unsigned short hb[3];
#pragma unroll
        for (int ch = 0; ch < 3; ++ch) {
            float hv = hp[(size_t)ch * IMG2];
            hsum += hv;                       // mask from exact fp32 (matches ref)
            hb[ch] = f2bf(hv);
            float hr = bf2f(hb[ch]);
            sh = fmaf(hr, hr, sh);            // s_h from rounded (consistent w/ gram)
        }
        *(uint4*)&heB[t * 8] =
            make_uint4((unsigned)hb[0] | ((unsigned)hb[1] << 16), (unsigned)hb[2], 0u, 0u);
        unsigned short n0 = hb[0] ^ 0x8000u, n1 = hb[1] ^ 0x8000u, n2 = hb[2] ^ 0x8000u;
        *(uint4*)&heA[t * 8] =
            make_uint4((unsigned)n0 | ((unsigned)n1 << 16), (unsigned)n2, 0u, 0u);
        s_lds[t] = sm - sh;
        m_lds[t] = (hsum >= 0.05f) ? 1.f : 0.f;
        if (t < 4) zq[t] = 0u;
    }
    __syncthreads();

    const int lane = t & 63, w = t >> 6;
    const int m = lane & 15, quad = lane >> 4;
    const short8* zfrag = (const short8*)zq;

    // A-side fragments for this wave's 4 row-tiles (hoisted out of j-loop)
    short8  Am[4], Ah[4];
    float4v sr4[4], mr4[4];
#pragma unroll
    for (int ii = 0; ii < 4; ++ii) {
        const int ri = (w * 4 + ii) * 16;
        Am[ii]  = *(const short8*)&xs[(ri + m) * XSTR + quad * 8];
        Ah[ii]  = (quad == 0) ? *(const short8*)&heA[(ri + m) * 8] : *zfrag;
        sr4[ii] = *(const float4v*)&s_lds[ri + quad * 4];
        mr4[ii] = *(const float4v*)&m_lds[ri + quad * 4];
    }

    float accv[4] = {0.f, 0.f, 0.f, 0.f};   // 4 independent fma chains (ILP)
#pragma unroll 2
    for (int j = 0; j < 16; ++j) {
        const int cj = j * 16;
        short8 Bm = *(const short8*)&xs[(cj + m) * XSTR + quad * 8];
        short8 Bh = (quad == 0) ? *(const short8*)&heB[(cj + m) * 8] : *zfrag;
        float  sc = s_lds[cj + m];
        float  mc = m_lds[cj + m];
#pragma unroll
        for (int ii = 0; ii < 4; ++ii) {
            float4v g = {0.f, 0.f, 0.f, 0.f};
            g = __builtin_amdgcn_mfma_f32_16x16x32_bf16(Ah[ii], Bh, g, 0, 0, 0); // -g_h
            g = __builtin_amdgcn_mfma_f32_16x16x32_bf16(Am[ii], Bm, g, 0, 0, 0); // +g_m
#pragma unroll
            for (int reg = 0; reg < 4; ++reg) {
                float tt = sr4[ii][reg] + sc;
                float rr = fmaf(-2.f, g[reg], tt);
                accv[ii] = fmaf(mr4[ii][reg] * mc, fabsf(rr), accv[ii]);
            }
        }
    }
    float acc = (accv[0] + accv[1]) + (accv[2] + accv[3]);

    // block reduction -> one atomic per block
#pragma unroll
    for (int off = 32; off > 0; off >>= 1)
        acc += __shfl_down(acc, off, 64);
    if (lane == 0) red[w] = acc;
    __syncthreads();
    if (t == 0)
        atomicAdd(out, (red[0] + red[1] + red[2] + red[3]) * scale);
}

extern "C" void kernel_launch(void* const* d_in, const int* in_sizes, int n_in,
                              void* d_out, int out_size, void* d_ws, size_t ws_size,
                              hipStream_t stream) {
    const float* msi   = (const float*)d_in[0];
    const float* he    = (const float*)d_in[1];
    const int*   i_idx = (const int*)d_in[2];
    const int*   j_idx = (const int*)d_in[3];
    const int    NB    = in_sizes[2];
    float*       out   = (float*)d_out;

    hipMemsetAsync(out, 0, sizeof(float) * out_size, stream);

    const float scale = 1.0f / ((float)(PSZ * PSZ) * (float)(NB / 5));
    corr_loss_kernel<<<NB, 256, 0, stream>>>(msi, he, i_idx, j_idx, out, scale);
}